// Round 10
// baseline (10223.647 us; speedup 1.0000x reference)
//
#include <hip/hip_runtime.h>
#include <hip/hip_bf16.h>
#include <math.h>

#define SEQ   32
#define BATCH 1024
#define NN    19
#define HH    128
#define NB    4            /* batch elements per block */
#define MR    (NB*NN)      /* 76 rows per block */
#define SAS   264          /* sA row stride (bf16): 528 B = 16B-aligned, 4-bank shift */
#define HS    132          /* h row stride (elems) */
#define NBLK  (BATCH/NB)   /* 256 blocks, 1 per CU */
#define NT    1024         /* 16 waves, 4 per SIMD */

typedef __attribute__((ext_vector_type(8))) short  bf16x8;
typedef __attribute__((ext_vector_type(4))) float  f32x4;

__device__ __forceinline__ unsigned short f2bf(float v) {
    __hip_bfloat16 b = __float2bfloat16(v);
    return *reinterpret_cast<unsigned short*>(&b);
}
__device__ __forceinline__ float bf2f(unsigned short u) {
    unsigned int x = ((unsigned int)u) << 16;
    return __uint_as_float(x);
}
__device__ __forceinline__ float hload(const unsigned short* p) { return bf2f(*p); }
__device__ __forceinline__ float hload(const float* p)          { return *p; }
__device__ __forceinline__ void  hstore(unsigned short* p, float v) { *p = f2bf(v); }
__device__ __forceinline__ void  hstore(float* p, float v)          { *p = v; }

// ---------------------------------------------------------------------------
// Setup 1: weight reorder/transpose: BT[j][col][k] = bf16(W[j*F + k][col])
// ---------------------------------------------------------------------------
__global__ __launch_bounds__(256) void wconv_kernel(
    const float* __restrict__ W, unsigned short* __restrict__ BT,
    int F, int O, int KP)
{
    int idx = blockIdx.x*256 + threadIdx.x;
    int total = 3*O*KP;
    if (idx >= total) return;
    int j   = idx / (O*KP);
    int r   = idx - j*(O*KP);
    int col = r / KP;
    int k   = r - col*KP;
    float v = (k < F) ? W[(size_t)(j*F + k)*O + col] : 0.f;
    BT[idx] = f2bf(v);
}

// ---------------------------------------------------------------------------
// Setup 2: T' as THREE 32x32 bf16 mats: Tg[j][m][n] = Tj[m,n] (zero-padded).
// T0=I, T1=S, T2=2S^2-I.
// ---------------------------------------------------------------------------
__global__ __launch_bounds__(256) void tprime_kernel(
    const float* __restrict__ S, unsigned short* __restrict__ Tg)
{
    __shared__ float sS[NN*NN], sS2[NN*NN];
    int tid = threadIdx.x;
    for (int i = tid; i < NN*NN; i += 256) sS[i] = S[i];
    __syncthreads();
    for (int i = tid; i < NN*NN; i += 256) {
        int m = i/NN, n = i - m*NN;
        float a = 0.f;
        for (int k = 0; k < NN; ++k) a += sS[m*NN+k]*sS[k*NN+n];
        sS2[i] = a;
    }
    __syncthreads();
    for (int i = tid; i < 3*32*32; i += 256) {
        int j = i >> 10, r = i & 1023;
        int m = r >> 5, n = r & 31;
        float v = 0.f;
        if (m < NN && n < NN) {
            float eye = (m == n) ? 1.f : 0.f;
            if (j == 0)      v = eye;
            else if (j == 1) v = sS[m*NN+n];
            else             v = 2.f*sS2[m*NN+n] - eye;
        }
        Tg[i] = f2bf(v);
    }
}

// ---------------------------------------------------------------------------
// Persistent kernel: 256 blocks x 1024 threads (16 waves, 4/SIMD).
// LDS: h0 bf16 | h1 f32 | sA | ub | Slab(16x 16x32) | TgL | xprev = 145,328 B
// ---------------------------------------------------------------------------
#define LDS_BYTES 145328

template<int KS, int OC, bool GATE, int XW, typename HT>
__device__ __forceinline__ void gconv_phase(
    const unsigned short* __restrict__ BT,   // (3, OC, KS*32) bf16
    const float* __restrict__ bias,
    HT* hL,
    unsigned short* sA,
    unsigned short* ub,
    unsigned short* SlabW,                   // this wave's 16x32 transpose slab
    const unsigned short* TgL,               // LDS 3x32x32 bf16
    int lane, int sgo)                       // sgo = this wave's 16-col base
{
    constexpr int KP  = KS*32;
    constexpr int TOT = 3*KS;
    constexpr int PF  = 6;                   // weight prefetch depth (96 B in flight)
    const int r16 = lane & 15, quad = lane >> 4;
    const size_t jstr = (size_t)OC*KP;
    const unsigned short* wbase = BT + (size_t)(sgo + r16)*KP + quad*8;

    // prefetch ring over flattened (j,ks)
    bf16x8 ring[PF];
    #pragma unroll
    for (int i = 0; i < PF; ++i)
        ring[i] = *(const bf16x8*)(wbase + (i/KS)*jstr + (i%KS)*32);

    f32x4 y[NB][2];
    #pragma unroll
    for (int b = 0; b < NB; ++b) { y[b][0] = (f32x4)0.f; y[b][1] = (f32x4)0.f; }

    #pragma unroll
    for (int j = 0; j < 3; ++j) {
        f32x4 acc[5];
        #pragma unroll
        for (int mt = 0; mt < 5; ++mt) acc[mt] = (f32x4)0.f;

        #pragma unroll
        for (int ks = 0; ks < KS; ++ks) {
            const int fl = j*KS + ks;
            bf16x8 bf = ring[fl % PF];
            #pragma unroll
            for (int mt = 0; mt < 5; ++mt) {
                bf16x8 af = *(const bf16x8*)&sA[(mt*16 + r16)*SAS + ks*32 + quad*8];
                acc[mt] = __builtin_amdgcn_mfma_f32_16x16x32_bf16(
                    af, bf, acc[mt], 0, 0, 0);
            }
            const int nf = fl + PF;
            if (nf < TOT)
                ring[fl % PF] = *(const bf16x8*)(wbase + (nf/KS)*jstr + (nf%KS)*32);
        }

        // mix-accumulate: y[b] += T'_j @ U_j  (U_j via per-wave LDS transpose)
        bf16x8 aft0 = *(const bf16x8*)&TgL[j*1024 + r16*32 + quad*8];
        bf16x8 aft1 = *(const bf16x8*)&TgL[j*1024 + (16 + r16)*32 + quad*8];
        #pragma unroll
        for (int b = 0; b < NB; ++b) {
            #pragma unroll
            for (int mt = 0; mt < 5; ++mt)
                #pragma unroll
                for (int reg = 0; reg < 4; ++reg) {
                    int gm = mt*16 + quad*4 + reg;
                    int n  = gm - b*NN;
                    if (n >= 0 && n < NN)
                        SlabW[r16*32 + n] = f2bf(acc[mt][reg]);
                }
            bf16x8 uf = *(const bf16x8*)&SlabW[r16*32 + quad*8];
            y[b][0] = __builtin_amdgcn_mfma_f32_16x16x32_bf16(aft0, uf, y[b][0], 0, 0, 0);
            y[b][1] = __builtin_amdgcn_mfma_f32_16x16x32_bf16(aft1, uf, y[b][1], 0, 0, 0);
        }
    }

    if (GATE) __syncthreads();   // gate epilogue rewrites sA (r*h)

    const float bv = bias[sgo + r16];
    #pragma unroll
    for (int b = 0; b < NB; ++b) {
        #pragma unroll
        for (int mt2 = 0; mt2 < 2; ++mt2)
            #pragma unroll
            for (int reg = 0; reg < 4; ++reg) {
                int m = mt2*16 + quad*4 + reg;
                if (m < NN) {
                    int o = sgo + r16;
                    float v = y[b][mt2][reg] + bv;
                    int row = b*NN + m;
                    if (GATE) {
                        float sg_ = 1.f/(1.f + __expf(-v));
                        if (o < HH)
                            sA[row*SAS + XW + o] = f2bf(sg_ * hload(&hL[row*HS + o]));
                        else
                            ub[row*HS + (o-HH)] = f2bf(sg_);
                    } else {
                        float c  = 2.f/(1.f + __expf(-2.f*v)) - 1.f;
                        float u  = bf2f(ub[row*HS + o]);
                        float ho = hload(&hL[row*HS + o]);
                        hstore(&hL[row*HS + o], u*ho + (1.f - u)*c);
                    }
                }
            }
    }
}

__global__ __launch_bounds__(NT, 4) void dcgru_persistent(
    const float* __restrict__ ihs,
    const unsigned short* __restrict__ BTg0, const float* __restrict__ bg0,
    const unsigned short* __restrict__ BTc0, const float* __restrict__ bc0,
    const unsigned short* __restrict__ BTg1, const float* __restrict__ bg1,
    const unsigned short* __restrict__ BTc1, const float* __restrict__ bc1,
    const float* __restrict__ Wp, const float* __restrict__ bp,
    const unsigned short* __restrict__ Tg,
    float* __restrict__ out)
{
    extern __shared__ char smem[];
    unsigned short* h0    = (unsigned short*)smem;                 // 20064
    float*          h1    = (float*)(smem + 20064);                // 40128
    unsigned short* sA    = (unsigned short*)(smem + 60192);       // 42240
    unsigned short* ub    = (unsigned short*)(smem + 102432);      // 20064
    unsigned short* Slab  = (unsigned short*)(smem + 122496);      // 16*512*2 = 16384
    unsigned short* TgL   = (unsigned short*)(smem + 138880);      // 3*1024*2 = 6144
    float*          xprev = (float*)(smem + 145024);               // 304

    const int tid  = threadIdx.x;
    const int lane = tid & 63;
    const int w    = tid >> 6;          // 0..15
    const int bb   = blockIdx.x * NB;
    unsigned short* SlabW = Slab + w*512;

    for (int i = tid; i < MR*HH; i += NT) {
        int row = i >> 7, f = i & 127;
        h0[row*HS + f] = f2bf(ihs[(size_t)bb*2432 + i]);
        h1[row*HS + f] = ihs[(size_t)(BATCH + bb)*2432 + i];
    }
    for (int i = tid; i < MR; i += NT) xprev[i] = 0.f;
    for (int i = tid; i < 3*1024; i += NT) TgL[i] = Tg[i];
    for (int i = lane; i < 512; i += 64) SlabW[i] = 0;

    const float wp0 = Wp[lane], wp1 = Wp[64 + lane], bpv = bp[0];
    __syncthreads();

    for (int t = 0; t < SEQ; ++t) {
        // ---- layer 0: sA = [xprev | h0 | 0-pad]  (K = 160) ----
        for (int idx = tid; idx < MR*160; idx += NT) {
            int row = idx/160, c = idx - row*160;
            unsigned short v;
            if (c == 0)       v = f2bf(xprev[row]);
            else if (c <= HH) v = h0[row*HS + (c-1)];
            else              v = 0;
            sA[row*SAS + c] = v;
        }
        __syncthreads();
        gconv_phase<5,256,true ,1>(BTg0, bg0, h0, sA, ub, SlabW, TgL, lane, w*16);
        __syncthreads();
        if (w < 8)
            gconv_phase<5,128,false,1>(BTc0, bc0, h0, sA, ub, SlabW, TgL, lane, w*16);
        __syncthreads();

        // ---- layer 1: sA = [h0 | h1]  (K = 256) ----
        for (int idx = tid; idx < MR*256; idx += NT) {
            int row = idx >> 8, c = idx & 255;
            sA[row*SAS + c] = (c < HH) ? h0[row*HS + c]
                                       : f2bf(h1[row*HS + (c-HH)]);
        }
        __syncthreads();
        gconv_phase<8,256,true ,HH>(BTg1, bg1, h1, sA, ub, SlabW, TgL, lane, w*16);
        __syncthreads();
        if (w < 8)
            gconv_phase<8,128,false,HH>(BTc1, bc1, h1, sA, ub, SlabW, TgL, lane, w*16);
        __syncthreads();

        // ---- projection: wave w -> batch w>>2, quarter of the nodes ----
        {
            int b  = w >> 2;
            int q  = w & 3;
            int n0 = q*5;
            int n1 = (q == 3) ? NN : n0 + 5;
            for (int n = n0; n < n1; ++n) {
                int row = b*NN + n;
                float s = h1[row*HS + lane]*wp0 + h1[row*HS + 64 + lane]*wp1;
                #pragma unroll
                for (int off = 32; off; off >>= 1) s += __shfl_down(s, off, 64);
                if (lane == 0) {
                    float v = s + bpv;
                    out[((size_t)t*BATCH + bb + b)*NN + n] = v;
                    xprev[row] = v;
                }
            }
        }
        __syncthreads();
    }
}

// ---------------------------------------------------------------------------
extern "C" void kernel_launch(void* const* d_in, const int* in_sizes, int n_in,
                              void* d_out, int out_size, void* d_ws, size_t ws_size,
                              hipStream_t stream) {
    const float* ihs = (const float*)d_in[1];
    const float* S   = (const float*)d_in[2];
    const float* Wg0 = (const float*)d_in[3];
    const float* bg0 = (const float*)d_in[4];
    const float* Wc0 = (const float*)d_in[5];
    const float* bc0 = (const float*)d_in[6];
    const float* Wg1 = (const float*)d_in[7];
    const float* bg1 = (const float*)d_in[8];
    const float* Wc1 = (const float*)d_in[9];
    const float* bc1 = (const float*)d_in[10];
    const float* Wp  = (const float*)d_in[11];
    const float* bp  = (const float*)d_in[12];
    float* out = (float*)d_out;

    unsigned short* ws = (unsigned short*)d_ws;
    unsigned short* Tg   = ws;               // 3*1024 = 3072 elems
    unsigned short* BTg0 = ws + 4096;        // 3*256*160 = 122880
    unsigned short* BTc0 = BTg0 + 122880;    // 3*128*160 = 61440
    unsigned short* BTg1 = BTc0 + 61440;     // 3*256*256 = 196608
    unsigned short* BTc1 = BTg1 + 196608;    // 3*128*256 = 98304

    tprime_kernel<<<1, 256, 0, stream>>>(S, Tg);
    wconv_kernel<<<(3*256*160+255)/256, 256, 0, stream>>>(Wg0, BTg0, 129, 256, 160);
    wconv_kernel<<<(3*128*160+255)/256, 256, 0, stream>>>(Wc0, BTc0, 129, 128, 160);
    wconv_kernel<<<(3*256*256+255)/256, 256, 0, stream>>>(Wg1, BTg1, 256, 256, 256);
    wconv_kernel<<<(3*128*256+255)/256, 256, 0, stream>>>(Wc1, BTc1, 256, 128, 256);

    hipFuncSetAttribute((const void*)dcgru_persistent,
                        hipFuncAttributeMaxDynamicSharedMemorySize, LDS_BYTES);

    dcgru_persistent<<<NBLK, NT, LDS_BYTES, stream>>>(
        ihs, BTg0, bg0, BTc0, bc0, BTg1, bg1, BTc1, bc1, Wp, bp, Tg, out);
}

// Round 11
// 2916.492 us; speedup vs baseline: 3.5055x; 3.5055x over previous
//
#include <hip/hip_runtime.h>
#include <hip/hip_bf16.h>
#include <math.h>

#define SEQ   32
#define BATCH 1024
#define NN    19
#define HH    128
#define NB    4            /* batch elements per block */
#define MR    (NB*NN)      /* 76 rows per block */
#define SAS   264          /* sA row stride (bf16): 528 B = 16B-aligned, 4-bank shift */
#define HS    132          /* h row stride (elems) */
#define UTS   72           /* Ut row stride (bf16): 144 B = 16B-aligned rows */
#define NBLK  (BATCH/NB)   /* 256 blocks, 1 per CU */
#define NT    1024         /* 16 waves, 4 per SIMD */

#define NCOPY 8            /* weight replicas (per-XCD) */
#define CPS   479232       /* elems per weight copy */
#define OFF_G0 0
#define OFF_C0 122880
#define OFF_G1 184320
#define OFF_C1 380928

typedef __attribute__((ext_vector_type(8))) short  bf16x8;
typedef __attribute__((ext_vector_type(4))) float  f32x4;

__device__ __forceinline__ unsigned short f2bf(float v) {
    __hip_bfloat16 b = __float2bfloat16(v);
    return *reinterpret_cast<unsigned short*>(&b);
}
__device__ __forceinline__ float bf2f(unsigned short u) {
    unsigned int x = ((unsigned int)u) << 16;
    return __uint_as_float(x);
}
__device__ __forceinline__ float hload(const unsigned short* p) { return bf2f(*p); }
__device__ __forceinline__ float hload(const float* p)          { return *p; }
__device__ __forceinline__ void  hstore(unsigned short* p, float v) { *p = f2bf(v); }
__device__ __forceinline__ void  hstore(float* p, float v)          { *p = v; }

// ---------------------------------------------------------------------------
// Setup 1: weight reorder/transpose + replicate x8:
// dst[r*CPS + col*KP + k] = bf16(W[j*F + k][col]) for r in 0..7
// ---------------------------------------------------------------------------
__global__ __launch_bounds__(256) void wconv_kernel(
    const float* __restrict__ W, unsigned short* __restrict__ dst,
    int F, int O, int KP)
{
    int idx = blockIdx.x*256 + threadIdx.x;
    int total = 3*O*KP;
    if (idx >= total) return;
    int j   = idx / (O*KP);
    int r   = idx - j*(O*KP);
    int col = r / KP;
    int k   = r - col*KP;
    float v = (k < F) ? W[(size_t)(j*F + k)*O + col] : 0.f;
    unsigned short b = f2bf(v);
    #pragma unroll
    for (int rep = 0; rep < NCOPY; ++rep)
        dst[(size_t)rep*CPS + idx] = b;
}

// ---------------------------------------------------------------------------
// Setup 2: T' (32 x 64) bf16: T'[m][j*19+n] = Tj[m,n]; T0=I, T1=S, T2=2S^2-I.
// ---------------------------------------------------------------------------
__global__ __launch_bounds__(256) void tprime_kernel(
    const float* __restrict__ S, unsigned short* __restrict__ Tg)
{
    __shared__ float sS[NN*NN], sS2[NN*NN];
    int tid = threadIdx.x;
    for (int i = tid; i < NN*NN; i += 256) sS[i] = S[i];
    __syncthreads();
    for (int i = tid; i < NN*NN; i += 256) {
        int m = i/NN, n = i - m*NN;
        float a = 0.f;
        for (int k = 0; k < NN; ++k) a += sS[m*NN+k]*sS[k*NN+n];
        sS2[i] = a;
    }
    __syncthreads();
    for (int i = tid; i < 32*64; i += 256) {
        int m = i >> 6, k = i & 63;
        float v = 0.f;
        if (m < NN && k < 3*NN) {
            int j = k / NN, n = k - j*NN;
            float eye = (m == n) ? 1.f : 0.f;
            if (j == 0)      v = eye;
            else if (j == 1) v = sS[m*NN+n];
            else             v = 2.f*sS2[m*NN+n] - eye;
        }
        Tg[i] = f2bf(v);
    }
}

// ---------------------------------------------------------------------------
// Persistent kernel: 256 blocks x 1024 threads (16 waves, 4/SIMD).
// ---------------------------------------------------------------------------
#define LDS_BYTES 159664

template<int KS, int OC, bool GATE, int XW, typename HT>
__device__ __forceinline__ void gconv_phase(
    const unsigned short* __restrict__ BT,   // (3, OC, KS*32) bf16
    const float* __restrict__ bias,
    HT* hL,
    unsigned short* sA,
    unsigned short* ub,
    unsigned short* UtW,                     // this wave's slab (16 x UTS)
    const bf16x8 (&tp)[2][2],
    int lane, int sgo)                       // sgo = this wave's 16-col base
{
    constexpr int KP = KS*32;
    const int r16 = lane & 15, quad = lane >> 4;

    f32x4 acc[3][5];
    #pragma unroll
    for (int j = 0; j < 3; ++j)
        #pragma unroll
        for (int mt = 0; mt < 5; ++mt) acc[j][mt] = (f32x4)0.f;

    // ---- main MFMA: U_j = x0 @ W_j for this wave's 16 cols ----
    #pragma unroll
    for (int ks = 0; ks < KS; ++ks) {
        bf16x8 af[5];
        #pragma unroll
        for (int mt = 0; mt < 5; ++mt)
            af[mt] = *(const bf16x8*)&sA[(mt*16 + r16)*SAS + ks*32 + quad*8];
        #pragma unroll
        for (int j = 0; j < 3; ++j) {
            const unsigned short* gp =
                BT + (size_t)(j*OC + sgo + r16)*KP + ks*32 + quad*8;
            bf16x8 bf = *(const bf16x8*)gp;
            #pragma unroll
            for (int mt = 0; mt < 5; ++mt)
                acc[j][mt] = __builtin_amdgcn_mfma_f32_16x16x32_bf16(
                    af[mt], bf, acc[j][mt], 0, 0, 0);
        }
    }

    if (GATE) __syncthreads();   // gate epilogue rewrites sA (r*h)

    const float bv = bias[sgo + r16];

    for (int b = 0; b < NB; ++b) {
        // scatter this batch's node rows into Ut (row = out col, col = j*19+n)
        #pragma unroll
        for (int j = 0; j < 3; ++j)
            #pragma unroll
            for (int mt = 0; mt < 5; ++mt)
                #pragma unroll
                for (int reg = 0; reg < 4; ++reg) {
                    int gm = mt*16 + quad*4 + reg;
                    int n  = gm - b*NN;
                    if (n >= 0 && n < NN)
                        UtW[r16*UTS + j*NN + n] = f2bf(acc[j][mt][reg]);
                }
        // mixing: y = T' @ U
        f32x4 y[2];
        y[0] = (f32x4)0.f; y[1] = (f32x4)0.f;
        #pragma unroll
        for (int kk = 0; kk < 2; ++kk) {
            bf16x8 uf = *(const bf16x8*)&UtW[r16*UTS + kk*32 + quad*8];
            y[0] = __builtin_amdgcn_mfma_f32_16x16x32_bf16(tp[0][kk], uf, y[0], 0, 0, 0);
            y[1] = __builtin_amdgcn_mfma_f32_16x16x32_bf16(tp[1][kk], uf, y[1], 0, 0, 0);
        }
        // epilogue
        #pragma unroll
        for (int mt2 = 0; mt2 < 2; ++mt2)
            #pragma unroll
            for (int reg = 0; reg < 4; ++reg) {
                int m = mt2*16 + quad*4 + reg;
                if (m < NN) {
                    int o = sgo + r16;
                    float v = y[mt2][reg] + bv;
                    int row = b*NN + m;
                    if (GATE) {
                        float sg_ = 1.f/(1.f + __expf(-v));
                        if (o < HH)
                            sA[row*SAS + XW + o] = f2bf(sg_ * hload(&hL[row*HS + o]));
                        else
                            ub[row*HS + (o-HH)] = f2bf(sg_);
                    } else {
                        float c  = 2.f/(1.f + __expf(-2.f*v)) - 1.f;
                        float u  = bf2f(ub[row*HS + o]);
                        float ho = hload(&hL[row*HS + o]);
                        hstore(&hL[row*HS + o], u*ho + (1.f - u)*c);
                    }
                }
            }
    }
}

__global__ __launch_bounds__(NT, 4) void dcgru_persistent(
    const float* __restrict__ ihs,
    const unsigned short* __restrict__ Wall,
    const float* __restrict__ bg0, const float* __restrict__ bc0,
    const float* __restrict__ bg1, const float* __restrict__ bc1,
    const float* __restrict__ Wp, const float* __restrict__ bp,
    const unsigned short* __restrict__ Tg,
    float* __restrict__ out)
{
    extern __shared__ char smem[];
    unsigned short* h0    = (unsigned short*)smem;                 // 20064
    float*          h1    = (float*)(smem + 20064);                // 40128
    unsigned short* sA    = (unsigned short*)(smem + 60192);       // 42240
    unsigned short* ub    = (unsigned short*)(smem + 102432);      // 20064
    unsigned short* Ut    = (unsigned short*)(smem + 122496);      // 36864
    float*          xprev = (float*)(smem + 159360);               // 304

    const int tid  = threadIdx.x;
    const int lane = tid & 63;
    const int w    = tid >> 6;          // 0..15
    const int bb   = blockIdx.x * NB;
    unsigned short* UtW = Ut + w*16*UTS;

    // per-XCD weight copy (blocks round-robin across XCDs by blockIdx)
    const unsigned short* Wcopy = Wall + (size_t)(blockIdx.x & (NCOPY-1))*CPS;
    const unsigned short* BTg0 = Wcopy + OFF_G0;
    const unsigned short* BTc0 = Wcopy + OFF_C0;
    const unsigned short* BTg1 = Wcopy + OFF_G1;
    const unsigned short* BTc1 = Wcopy + OFF_C1;

    for (int i = tid; i < MR*HH; i += NT) {
        int row = i >> 7, f = i & 127;
        h0[row*HS + f] = f2bf(ihs[(size_t)bb*2432 + i]);
        h1[row*HS + f] = ihs[(size_t)(BATCH + bb)*2432 + i];
    }
    for (int i = tid; i < MR; i += NT) xprev[i] = 0.f;
    for (int i = lane; i < 16*UTS; i += 64) UtW[i] = 0;

    bf16x8 tp[2][2];
    {
        const int r16 = lane & 15, quad = lane >> 4;
        #pragma unroll
        for (int mt2 = 0; mt2 < 2; ++mt2)
            #pragma unroll
            for (int kk = 0; kk < 2; ++kk)
                tp[mt2][kk] = *(const bf16x8*)&Tg[(mt2*16 + r16)*64 + kk*32 + quad*8];
    }
    const float wp0 = Wp[lane], wp1 = Wp[64 + lane], bpv = bp[0];
    __syncthreads();

    for (int t = 0; t < SEQ; ++t) {
        // ---- layer 0: sA = [xprev | h0 | 0-pad]  (K = 160) ----
        for (int idx = tid; idx < MR*160; idx += NT) {
            int row = idx/160, c = idx - row*160;
            unsigned short v;
            if (c == 0)       v = f2bf(xprev[row]);
            else if (c <= HH) v = h0[row*HS + (c-1)];
            else              v = 0;
            sA[row*SAS + c] = v;
        }
        __syncthreads();
        gconv_phase<5,256,true ,1>(BTg0, bg0, h0, sA, ub, UtW, tp, lane, w*16);
        __syncthreads();
        if (w < 8)
            gconv_phase<5,128,false,1>(BTc0, bc0, h0, sA, ub, UtW, tp, lane, w*16);
        __syncthreads();

        // ---- layer 1: sA = [h0 | h1]  (K = 256) ----
        for (int idx = tid; idx < MR*256; idx += NT) {
            int row = idx >> 8, c = idx & 255;
            sA[row*SAS + c] = (c < HH) ? h0[row*HS + c]
                                       : f2bf(h1[row*HS + (c-HH)]);
        }
        __syncthreads();
        gconv_phase<8,256,true ,HH>(BTg1, bg1, h1, sA, ub, UtW, tp, lane, w*16);
        __syncthreads();
        if (w < 8)
            gconv_phase<8,128,false,HH>(BTc1, bc1, h1, sA, ub, UtW, tp, lane, w*16);
        __syncthreads();

        // ---- projection: wave w -> batch w>>2, quarter of the nodes ----
        {
            int b  = w >> 2;
            int q  = w & 3;
            int n0 = q*5;
            int n1 = (q == 3) ? NN : n0 + 5;
            for (int n = n0; n < n1; ++n) {
                int row = b*NN + n;
                float s = h1[row*HS + lane]*wp0 + h1[row*HS + 64 + lane]*wp1;
                #pragma unroll
                for (int off = 32; off; off >>= 1) s += __shfl_down(s, off, 64);
                if (lane == 0) {
                    float v = s + bpv;
                    out[((size_t)t*BATCH + bb + b)*NN + n] = v;
                    xprev[row] = v;
                }
            }
        }
        __syncthreads();
    }
}

// ---------------------------------------------------------------------------
extern "C" void kernel_launch(void* const* d_in, const int* in_sizes, int n_in,
                              void* d_out, int out_size, void* d_ws, size_t ws_size,
                              hipStream_t stream) {
    const float* ihs = (const float*)d_in[1];
    const float* S   = (const float*)d_in[2];
    const float* Wg0 = (const float*)d_in[3];
    const float* bg0 = (const float*)d_in[4];
    const float* Wc0 = (const float*)d_in[5];
    const float* bc0 = (const float*)d_in[6];
    const float* Wg1 = (const float*)d_in[7];
    const float* bg1 = (const float*)d_in[8];
    const float* Wc1 = (const float*)d_in[9];
    const float* bc1 = (const float*)d_in[10];
    const float* Wp  = (const float*)d_in[11];
    const float* bp  = (const float*)d_in[12];
    float* out = (float*)d_out;

    unsigned short* ws = (unsigned short*)d_ws;
    unsigned short* Tg   = ws;               // 2048 elems used
    unsigned short* Wall = ws + 4096;        // 8 copies x 479232 elems

    tprime_kernel<<<1, 256, 0, stream>>>(S, Tg);
    wconv_kernel<<<(3*256*160+255)/256, 256, 0, stream>>>(Wg0, Wall + OFF_G0, 129, 256, 160);
    wconv_kernel<<<(3*128*160+255)/256, 256, 0, stream>>>(Wc0, Wall + OFF_C0, 129, 128, 160);
    wconv_kernel<<<(3*256*256+255)/256, 256, 0, stream>>>(Wg1, Wall + OFF_G1, 256, 256, 256);
    wconv_kernel<<<(3*128*256+255)/256, 256, 0, stream>>>(Wc1, Wall + OFF_C1, 256, 128, 256);

    hipFuncSetAttribute((const void*)dcgru_persistent,
                        hipFuncAttributeMaxDynamicSharedMemorySize, LDS_BYTES);

    dcgru_persistent<<<NBLK, NT, LDS_BYTES, stream>>>(
        ihs, Wall, bg0, bc0, bg1, bc1, Wp, bp, Tg, out);
}